// Round 1
// baseline (440.465 us; speedup 1.0000x reference)
//
#include <hip/hip_runtime.h>
#include <math.h>

#define NB 16   // batches
#define NP 900  // predictions (solver columns)
#define NC 91   // classes
#define NT 100  // targets (solver rows)

// ---------------------------------------------------------------------------
// Cost kernel: Ct[b][m][n] = 5*l1 - 2*iou - softmax(cls_pred[b,n])[cls_gt[b,m]]
// (transposed layout: solver rows = targets)
// ---------------------------------------------------------------------------
__global__ __launch_bounds__(256) void cost_kernel(
    const float* __restrict__ cls_pred,   // [B,N,K]
    const float* __restrict__ bb_pred,    // [B,N,4]
    const int*   __restrict__ cls_gt,     // [B,M]
    const float* __restrict__ bb_gt,      // [B,M,4]
    float* __restrict__ Ct)               // [B,M,N]
{
    const int b = blockIdx.y;
    const int n = blockIdx.x * 256 + threadIdx.x;

    __shared__ float gx0[NT], gy0[NT], gx1[NT], gy1[NT], garea[NT];
    __shared__ int   gcls[NT];
    for (int m = threadIdx.x; m < NT; m += 256) {
        const float x0 = bb_gt[((size_t)b*NT + m)*4 + 0];
        const float y0 = bb_gt[((size_t)b*NT + m)*4 + 1];
        const float x1 = bb_gt[((size_t)b*NT + m)*4 + 2];
        const float y1 = bb_gt[((size_t)b*NT + m)*4 + 3];
        gx0[m] = x0; gy0[m] = y0; gx1[m] = x1; gy1[m] = y1;
        garea[m] = (x1 - x0) * (y1 - y0);
        gcls[m]  = cls_gt[b*NT + m];
    }
    __syncthreads();
    if (n >= NP) return;

    const float4 bp = *reinterpret_cast<const float4*>(bb_pred + ((size_t)b*NP + n)*4);
    const float parea = (bp.z - bp.x) * (bp.w - bp.y);

    const float* crow = cls_pred + ((size_t)b*NP + n)*NC;
    float mx = -INFINITY;
    for (int k = 0; k < NC; ++k) mx = fmaxf(mx, crow[k]);
    float s = 0.f;
    for (int k = 0; k < NC; ++k) s += expf(crow[k] - mx);

    float* out = Ct + (size_t)b*NT*NP + n;
    for (int m = 0; m < NT; ++m) {
        const float l1 = fabsf(bp.x - gx0[m]) + fabsf(bp.y - gy0[m]) +
                         fabsf(bp.z - gx1[m]) + fabsf(bp.w - gy1[m]);
        const float xm = fmaxf(bp.x, gx0[m]);
        const float ym = fmaxf(bp.y, gy0[m]);
        const float xM = fminf(bp.z, gx1[m]);
        const float yM = fminf(bp.w, gy1[m]);
        const float inter = fmaxf(xM - xm, 0.f) * fmaxf(yM - ym, 0.f);
        const float uni = parea + garea[m] - inter;
        const float iou = inter / (uni + 1e-6f);
        const float pc  = expf(crow[gcls[m]] - mx) / s;
        out[(size_t)m*NP] = 5.0f*l1 - 2.0f*iou - pc;
    }
}

// ---------------------------------------------------------------------------
// JV shortest-augmenting-path solver, one block per batch. Faithful fp64 port
// of the reference _solve() on the transposed (100 x 900) cost matrix.
// ---------------------------------------------------------------------------
__global__ __launch_bounds__(256) void jv_kernel(
    const float* __restrict__ Ct,   // [B,M,N]
    int* __restrict__ out)          // preds [B,M] then tgts [B,M] (int32)
{
    const int b   = blockIdx.x;
    const int tid = threadIdx.x;

    __shared__ double v_[NP + 1];
    __shared__ double minv[NP + 1];
    __shared__ int    way[NP + 1];
    __shared__ int    used[NP + 1];
    __shared__ int    p[NP + 1];
    __shared__ double u_[NT + 1];
    __shared__ double wv[4];
    __shared__ int    wj[4];
    __shared__ int    j0_s;
    __shared__ double delta_s;

    for (int j = tid; j <= NP; j += 256) { v_[j] = 0.0; p[j] = 0; }
    if (tid <= NT) u_[tid] = 0.0;
    __syncthreads();

    const float* Cb = Ct + (size_t)b*NT*NP;

    for (int i = 1; i <= NT; ++i) {
        if (tid == 0) { p[0] = i; j0_s = 0; }
        for (int j = tid; j <= NP; j += 256) {
            minv[j] = INFINITY; used[j] = 0; way[j] = 0;
        }
        __syncthreads();

        while (true) {
            const int j0 = j0_s;
            if (tid == 0) used[j0] = 1;
            const int    i0  = p[j0];
            const double ui0 = u_[i0];
            const float* crow = Cb + (size_t)(i0 - 1)*NP;
            __syncthreads();   // used[j0] visible before scan

            // scan: update minv/way over unused cols; local argmin of minv
            double best  = INFINITY;
            int    bestj = 0x7fffffff;
            #pragma unroll
            for (int r = 0; r < 4; ++r) {
                const int j = 1 + tid + 256*r;
                if (j <= NP && !used[j]) {
                    const double cur = (double)crow[j - 1] - ui0 - v_[j];
                    if (cur < minv[j]) { minv[j] = cur; way[j] = j0; }
                    const double mv = minv[j];
                    if (mv < best) { best = mv; bestj = j; }
                    else if (mv == best && j < bestj) bestj = j;
                }
            }
            // wave (64-lane) butterfly reduce, tie-break = smallest index
            #pragma unroll
            for (int off = 32; off >= 1; off >>= 1) {
                const double ov = __shfl_xor(best, off, 64);
                const int    oj = __shfl_xor(bestj, off, 64);
                if (ov < best || (ov == best && oj < bestj)) { best = ov; bestj = oj; }
            }
            if ((tid & 63) == 0) { wv[tid >> 6] = best; wj[tid >> 6] = bestj; }
            __syncthreads();
            if (tid == 0) {
                double bv = wv[0]; int bj = wj[0];
                for (int w = 1; w < 4; ++w) {
                    if (wv[w] < bv || (wv[w] == bv && wj[w] < bj)) { bv = wv[w]; bj = wj[w]; }
                }
                delta_s = bv;
                j0_s    = bj;
            }
            __syncthreads();

            // dual updates
            const double delta = delta_s;
            for (int j = tid; j <= NP; j += 256) {
                if (used[j]) { u_[p[j]] += delta; v_[j] -= delta; }
                else if (j >= 1) minv[j] -= delta;
            }
            __syncthreads();

            if (p[j0_s] == 0) break;
        }

        // augment along the alternating path (serial, trivial)
        if (tid == 0) {
            int j0 = j0_s;
            while (j0 != 0) { const int j1 = way[j0]; p[j0] = p[j1]; j0 = j1; }
        }
        __syncthreads();
    }

    // emit matches sorted by pred index (ascending j order)
    if (tid == 0) {
        int cnt = 0;
        for (int j = 1; j <= NP; ++j) {
            if (p[j] != 0) {
                out[b*NT + cnt]         = j - 1;      // pred index
                out[NB*NT + b*NT + cnt] = p[j] - 1;   // target index
                ++cnt;
            }
        }
    }
}

extern "C" void kernel_launch(void* const* d_in, const int* in_sizes, int n_in,
                              void* d_out, int out_size, void* d_ws, size_t ws_size,
                              hipStream_t stream)
{
    const float* cls_pred = (const float*)d_in[0];
    const float* bb_pred  = (const float*)d_in[1];
    const int*   cls_gt   = (const int*)d_in[2];
    const float* bb_gt    = (const float*)d_in[3];

    float* Ct = (float*)d_ws;   // B*M*N floats = 5.76 MB

    dim3 gcost((NP + 255)/256, NB);
    cost_kernel<<<gcost, 256, 0, stream>>>(cls_pred, bb_pred, cls_gt, bb_gt, Ct);
    jv_kernel<<<NB, 256, 0, stream>>>(Ct, (int*)d_out);
}